// Round 1
// baseline (1208.316 us; speedup 1.0000x reference)
//
#include <hip/hip_runtime.h>

// LSTM_1030792151143: 2-layer LSTM (B=2048, T=1000, F=40, H1=8, H2=6) + tanh + FC + sigmoid.
// One wave (64 lanes) per batch element; lane g=lane&31 owns layer-1 gate g
// (and, clamped, layer-2 gate min(g,23)). x rows are wave-uniform -> scalar loads.
// Input dot for step t+1 is software-pipelined behind step t's recurrent work.

constexpr int Bn = 2048, Tn = 1000, Fn = 40;
constexpr int H1n = 8, H2n = 6;
constexpr int G2n = 24;

__device__ __forceinline__ float frcp(float x) { return __builtin_amdgcn_rcpf(x); }
// a * sigmoid-core + c :  A*rcp(1+exp(B*x))+C   (sigmoid: 1,-1,0; tanh: 2,-2,-1)
__device__ __forceinline__ float act_abc(float A, float Bc, float C, float x) {
    return fmaf(A, frcp(1.0f + __expf(Bc * x)), C);
}
__device__ __forceinline__ float ftanh(float x) {
    return fmaf(2.0f, frcp(1.0f + __expf(-2.0f * x)), -1.0f);
}

__global__ __launch_bounds__(256, 2) void lstm_fused(
    const float* __restrict__ x,
    const float* __restrict__ W_ih1, const float* __restrict__ W_hh1,
    const float* __restrict__ b_ih1, const float* __restrict__ b_hh1,
    const float* __restrict__ W_ih2, const float* __restrict__ W_hh2,
    const float* __restrict__ b_ih2, const float* __restrict__ b_hh2,
    const float* __restrict__ W_fc,  const float* __restrict__ b_fc,
    float* __restrict__ out)
{
    __shared__ float sm[4][32];  // per-wave: [0..7]=h1, [8..15]=tanh(h1), [16..21]=h2

    const int lane  = threadIdx.x & 63;
    const int wslot = __builtin_amdgcn_readfirstlane((int)(threadIdx.x >> 6));
    const int b     = blockIdx.x * 4 + wslot;   // 512 blocks * 4 waves = 2048

    const int g  = lane & 31;                   // layer-1 gate owned
    const int g2 = (g < G2n) ? g : (G2n - 1);   // layer-2 gate (clamped duplicate)
    const int j1 = lane & 7;                    // H1 index this lane tracks
    const int j2 = g % H2n;                     // H2 index this lane tracks

    // ---- preload weights into VGPRs (one-time, uncoalesced but tiny) ----
    float wih1[Fn];
#pragma unroll
    for (int k = 0; k < Fn; ++k) wih1[k] = W_ih1[g * Fn + k];
    float whh1[H1n];
#pragma unroll
    for (int k = 0; k < H1n; ++k) whh1[k] = W_hh1[g * H1n + k];
    const float bias1 = b_ih1[g] + b_hh1[g];

    float wih2[H1n];
#pragma unroll
    for (int k = 0; k < H1n; ++k) wih2[k] = W_ih2[g2 * H1n + k];
    float whh2[H2n];
#pragma unroll
    for (int k = 0; k < H2n; ++k) whh2[k] = W_hh2[g2 * H2n + k];
    const float bias2 = b_ih2[g2] + b_hh2[g2];

    // activation coefficients for the gate each lane owns (branchless act)
    const bool t1 = (g >= 16 && g < 24);          // L1 cell gate -> tanh
    const float A1 = t1 ? 2.f : 1.f, Bc1 = t1 ? -2.f : -1.f, C1 = t1 ? -1.f : 0.f;
    const bool t2 = (g2 >= 12 && g2 < 18);        // L2 cell gate -> tanh
    const float A2 = t2 ? 2.f : 1.f, Bc2 = t2 ? -2.f : -1.f, C2 = t2 ? -1.f : 0.f;

    // ---- state (replicated across lanes where needed) ----
    float h1all[H1n], th1all[H1n], h2all[H2n];
#pragma unroll
    for (int k = 0; k < H1n; ++k) { h1all[k] = 0.f; th1all[k] = 0.f; }
#pragma unroll
    for (int k = 0; k < H2n; ++k) h2all[k] = 0.f;
    float c1 = 0.f, c2 = 0.f;

    const float* __restrict__ xb = x + (size_t)b * Tn * Fn;  // wave-uniform

    // prologue: layer-1 input dot for t=0
    float xg;
    {
        float a = bias1;
#pragma unroll
        for (int k = 0; k < Fn; ++k) a = fmaf(xb[k], wih1[k], a);
        xg = a;
    }

    for (int t = 0; t < Tn; ++t) {
        // ---- phase A: prefetch next x row (uniform -> scalar loads) ----
        const float* __restrict__ xn = xb + (size_t)((t + 1 < Tn) ? (t + 1) : t) * Fn;
        float xs[Fn];
#pragma unroll
        for (int k = 0; k < Fn; ++k) xs[k] = xn[k];

        // ---- phase B1: layer-1 recurrent part ----
        float a = xg;
#pragma unroll
        for (int k = 0; k < H1n; ++k) a = fmaf(h1all[k], whh1[k], a);
        const float gv = act_abc(A1, Bc1, C1, a);

        const float iv  = __shfl(gv, j1);
        const float fv  = __shfl(gv, j1 + 8);
        const float gcv = __shfl(gv, j1 + 16);
        const float ov  = __shfl(gv, j1 + 24);
        c1 = fmaf(fv, c1, iv * gcv);
        const float h1v  = ov * ftanh(c1);
        const float th1v = ftanh(h1v);

        if (lane < H1n) { sm[wslot][lane] = h1v; sm[wslot][8 + lane] = th1v; }
        __builtin_amdgcn_wave_barrier();
        {
            const float4 v0 = *(const float4*)&sm[wslot][0];
            const float4 v1 = *(const float4*)&sm[wslot][4];
            const float4 v2 = *(const float4*)&sm[wslot][8];
            const float4 v3 = *(const float4*)&sm[wslot][12];
            h1all[0] = v0.x; h1all[1] = v0.y; h1all[2] = v0.z; h1all[3] = v0.w;
            h1all[4] = v1.x; h1all[5] = v1.y; h1all[6] = v1.z; h1all[7] = v1.w;
            th1all[0] = v2.x; th1all[1] = v2.y; th1all[2] = v2.z; th1all[3] = v2.w;
            th1all[4] = v3.x; th1all[5] = v3.y; th1all[6] = v3.z; th1all[7] = v3.w;
        }

        // ---- phase B2: layer-2 (full step, same t) ----
        float a2 = bias2;
#pragma unroll
        for (int k = 0; k < H1n; ++k) a2 = fmaf(th1all[k], wih2[k], a2);
#pragma unroll
        for (int k = 0; k < H2n; ++k) a2 = fmaf(h2all[k], whh2[k], a2);
        const float gv2 = act_abc(A2, Bc2, C2, a2);

        const float iv2  = __shfl(gv2, j2);
        const float fv2  = __shfl(gv2, j2 + 6);
        const float gcv2 = __shfl(gv2, j2 + 12);
        const float ov2  = __shfl(gv2, j2 + 18);
        c2 = fmaf(fv2, c2, iv2 * gcv2);
        const float h2v = ov2 * ftanh(c2);

        if (lane < H2n) sm[wslot][16 + lane] = h2v;
        __builtin_amdgcn_wave_barrier();
        {
            const float4 v4 = *(const float4*)&sm[wslot][16];
            const float2 v5 = *(const float2*)&sm[wslot][20];
            h2all[0] = v4.x; h2all[1] = v4.y; h2all[2] = v4.z; h2all[3] = v4.w;
            h2all[4] = v5.x; h2all[5] = v5.y;
        }

        // ---- phase C: layer-1 input dot for t+1 (prefetched xs now ready) ----
        float an = bias1;
#pragma unroll
        for (int k = 0; k < Fn; ++k) an = fmaf(xs[k], wih1[k], an);
        xg = an;
    }

    // ---- epilogue: FC + sigmoid on tanh(h2[T-1]) ----
    if (lane == 0) {
        float a = b_fc[0];
#pragma unroll
        for (int k = 0; k < H2n; ++k) a = fmaf(ftanh(h2all[k]), W_fc[k], a);
        out[b] = frcp(1.0f + __expf(-a));
    }
}

extern "C" void kernel_launch(void* const* d_in, const int* in_sizes, int n_in,
                              void* d_out, int out_size, void* d_ws, size_t ws_size,
                              hipStream_t stream) {
    (void)in_sizes; (void)n_in; (void)d_ws; (void)ws_size; (void)out_size;
    const float* x     = (const float*)d_in[0];
    const float* W_ih1 = (const float*)d_in[1];
    const float* W_hh1 = (const float*)d_in[2];
    const float* b_ih1 = (const float*)d_in[3];
    const float* b_hh1 = (const float*)d_in[4];
    const float* W_ih2 = (const float*)d_in[5];
    const float* W_hh2 = (const float*)d_in[6];
    const float* b_ih2 = (const float*)d_in[7];
    const float* b_hh2 = (const float*)d_in[8];
    const float* W_fc  = (const float*)d_in[9];
    const float* b_fc  = (const float*)d_in[10];
    float* out = (float*)d_out;

    dim3 grid(Bn / 4);   // 512 blocks, 4 waves (batches) each
    dim3 block(256);
    lstm_fused<<<grid, block, 0, stream>>>(x, W_ih1, W_hh1, b_ih1, b_hh1,
                                           W_ih2, W_hh2, b_ih2, b_hh2,
                                           W_fc, b_fc, out);
}

// Round 2
// 1204.129 us; speedup vs baseline: 1.0035x; 1.0035x over previous
//
#include <hip/hip_runtime.h>

// LSTM_1030792151143: 2-layer LSTM (B=2048, T=1000, F=40, H1=8, H2=6) + tanh + FC + sigmoid.
//
// Round 2 structure:
//   Pass 1 (xg_pass): xg[b][t][g] = b_ih1[g]+b_hh1[g] + sum_k x[b][t][k]*W_ih1[g][k]
//     - no t-dependency, 8192 waves (32/CU), scalar x-row loads, coalesced stores to d_ws.
//   Pass 2 (lstm_rec): recurrence only. 1 vector load (vmcnt) per step, depth-8 register
//     prefetch; h1/tanh(h1)/h2 broadcast via v_readlane (no LDS round-trips, no lgkmcnt
//     entanglement with prefetch). Gate gathers via __shfl (ds_bpermute).
//   Fallback: if ws_size < 262 MB, run the round-1 fused kernel (passed at 903 us).

constexpr int Bn = 2048, Tn = 1000, Fn = 40;
constexpr int H1n = 8, H2n = 6;
constexpr int G1n = 32, G2n = 24;
constexpr int PF = 8;   // xg prefetch depth (steps)

__device__ __forceinline__ float frcp(float x) { return __builtin_amdgcn_rcpf(x); }
__device__ __forceinline__ float act_abc(float A, float Bc, float C, float x) {
    return fmaf(A, frcp(1.0f + __expf(Bc * x)), C);   // sigmoid: (1,-1,0); tanh: (2,-2,-1)
}
__device__ __forceinline__ float ftanh(float x) {
    return fmaf(2.0f, frcp(1.0f + __expf(-2.0f * x)), -1.0f);
}
__device__ __forceinline__ float bcast(float v, int k) {   // lane-k broadcast via readlane
    return __uint_as_float(__builtin_amdgcn_readlane(__float_as_uint(v), k));
}

// ---------------- Pass 1: input projection (no recurrence) ----------------
__global__ __launch_bounds__(256, 8) void xg_pass(
    const float* __restrict__ x, const float* __restrict__ W_ih1,
    const float* __restrict__ b_ih1, const float* __restrict__ b_hh1,
    float* __restrict__ xg)
{
    const int lane  = threadIdx.x & 63;
    const int wslot = __builtin_amdgcn_readfirstlane((int)(threadIdx.x >> 6));
    const int b     = blockIdx.x;                 // 2048 blocks, one batch each
    const int g     = lane & 31;
    constexpr int TC = Tn / 4;                    // 250 steps per wave
    const int t0 = wslot * TC;

    float w[Fn];
#pragma unroll
    for (int k = 0; k < Fn; ++k) w[k] = W_ih1[g * Fn + k];
    const float bias = b_ih1[g] + b_hh1[g];

    const float* __restrict__ xb = x  + (size_t)b * Tn * Fn;
    float* __restrict__       og = xg + (size_t)b * Tn * G1n;

#pragma unroll 2
    for (int t = t0; t < t0 + TC; ++t) {
        const float* __restrict__ row = xb + (size_t)t * Fn;   // wave-uniform -> s_load
        float a0 = bias, a1 = 0.f, a2 = 0.f, a3 = 0.f;
#pragma unroll
        for (int k = 0; k < Fn; k += 4) {
            a0 = fmaf(row[k + 0], w[k + 0], a0);
            a1 = fmaf(row[k + 1], w[k + 1], a1);
            a2 = fmaf(row[k + 2], w[k + 2], a2);
            a3 = fmaf(row[k + 3], w[k + 3], a3);
        }
        if (lane < G1n) og[(size_t)t * G1n + g] = (a0 + a1) + (a2 + a3);
    }
}

// ---------------- Pass 2: recurrence only ----------------
__global__ __launch_bounds__(256, 2) void lstm_rec(
    const float* __restrict__ xg,
    const float* __restrict__ W_hh1,
    const float* __restrict__ W_ih2, const float* __restrict__ W_hh2,
    const float* __restrict__ b_ih2, const float* __restrict__ b_hh2,
    const float* __restrict__ W_fc,  const float* __restrict__ b_fc,
    float* __restrict__ out)
{
    const int lane  = threadIdx.x & 63;
    const int wslot = __builtin_amdgcn_readfirstlane((int)(threadIdx.x >> 6));
    const int b     = blockIdx.x * 4 + wslot;     // 512 blocks * 4 waves

    const int g  = lane & 31;                     // L1 gate owned
    const int g2 = (g < G2n) ? g : (G2n - 1);     // L2 gate (clamped dup)
    const int j1 = lane & 7;
    const int j2 = g % H2n;

    float whh1[H1n];
#pragma unroll
    for (int k = 0; k < H1n; ++k) whh1[k] = W_hh1[g * H1n + k];
    float wih2[H1n];
#pragma unroll
    for (int k = 0; k < H1n; ++k) wih2[k] = W_ih2[g2 * H1n + k];
    float whh2[H2n];
#pragma unroll
    for (int k = 0; k < H2n; ++k) whh2[k] = W_hh2[g2 * H2n + k];
    const float bias2 = b_ih2[g2] + b_hh2[g2];

    const bool t1 = (g >= 16 && g < 24);          // L1 cell gate -> tanh
    const float A1 = t1 ? 2.f : 1.f, Bc1 = t1 ? -2.f : -1.f, C1 = t1 ? -1.f : 0.f;
    const bool t2 = (g2 >= 12 && g2 < 18);        // L2 cell gate -> tanh
    const float A2 = t2 ? 2.f : 1.f, Bc2 = t2 ? -2.f : -1.f, C2 = t2 ? -1.f : 0.f;

    float c1 = 0.f, c2 = 0.f;
    float h1s[H1n], th1s[H1n], h2s[H2n];
#pragma unroll
    for (int k = 0; k < H1n; ++k) { h1s[k] = 0.f; th1s[k] = 0.f; }
#pragma unroll
    for (int k = 0; k < H2n; ++k) h2s[k] = 0.f;

    const float* __restrict__ xgb = xg + (size_t)b * Tn * G1n + g;

    float buf[PF];
#pragma unroll
    for (int i = 0; i < PF; ++i) buf[i] = xgb[(size_t)i * G1n];

    float a_pre = buf[0];                          // t=0: h1=0 so preact = xg

#pragma unroll 8
    for (int t = 0; t < Tn; ++t) {
        const int r = t & (PF - 1);                // constant after unroll-8

        // prefetch xg(t+PF) — vmcnt, decoupled from DS waits
        int tp = t + PF; if (tp >= Tn) tp = Tn - 1;
        const float pf = xgb[(size_t)tp * G1n];

        // ---- layer 1 gate + state ----
        const float gv  = act_abc(A1, Bc1, C1, a_pre);
        const float iv  = __shfl(gv, j1);
        const float fv  = __shfl(gv, j1 + 8);
        const float gcv = __shfl(gv, j1 + 16);
        const float ov  = __shfl(gv, j1 + 24);
        c1 = fmaf(fv, c1, iv * gcv);
        const float h1v  = ov * ftanh(c1);
        const float th1v = ftanh(h1v);

#pragma unroll
        for (int k = 0; k < H1n; ++k) h1s[k]  = bcast(h1v, k);
#pragma unroll
        for (int k = 0; k < H1n; ++k) th1s[k] = bcast(th1v, k);

        buf[r] = pf;

        // ---- next-step L1 preactivation (pipelined) ----
        {
            float a0 = buf[(r + 1) & (PF - 1)], a1 = 0.f;
#pragma unroll
            for (int k = 0; k < H1n; k += 2) {
                a0 = fmaf(h1s[k],     whh1[k],     a0);
                a1 = fmaf(h1s[k + 1], whh1[k + 1], a1);
            }
            a_pre = a0 + a1;
        }

        // ---- layer 2 full step ----
        float a20 = bias2, a21 = 0.f;
#pragma unroll
        for (int k = 0; k < H1n; k += 2) {
            a20 = fmaf(th1s[k],     wih2[k],     a20);
            a21 = fmaf(th1s[k + 1], wih2[k + 1], a21);
        }
#pragma unroll
        for (int k = 0; k < H2n; k += 2) {
            a20 = fmaf(h2s[k],     whh2[k],     a20);
            a21 = fmaf(h2s[k + 1], whh2[k + 1], a21);
        }
        const float gv2  = act_abc(A2, Bc2, C2, a20 + a21);
        const float iv2  = __shfl(gv2, j2);
        const float fv2  = __shfl(gv2, j2 + 6);
        const float gcv2 = __shfl(gv2, j2 + 12);
        const float ov2  = __shfl(gv2, j2 + 18);
        c2 = fmaf(fv2, c2, iv2 * gcv2);
        const float h2v = ov2 * ftanh(c2);

#pragma unroll
        for (int k = 0; k < H2n; ++k) h2s[k] = bcast(h2v, k);
    }

    if (lane == 0) {
        float a = b_fc[0];
#pragma unroll
        for (int k = 0; k < H2n; ++k) a = fmaf(ftanh(h2s[k]), W_fc[k], a);
        out[b] = frcp(1.0f + __expf(-a));
    }
}

// ---------------- Round-1 fused kernel (fallback if ws too small) ----------------
__global__ __launch_bounds__(256, 2) void lstm_fused(
    const float* __restrict__ x,
    const float* __restrict__ W_ih1, const float* __restrict__ W_hh1,
    const float* __restrict__ b_ih1, const float* __restrict__ b_hh1,
    const float* __restrict__ W_ih2, const float* __restrict__ W_hh2,
    const float* __restrict__ b_ih2, const float* __restrict__ b_hh2,
    const float* __restrict__ W_fc,  const float* __restrict__ b_fc,
    float* __restrict__ out)
{
    __shared__ float sm[4][32];

    const int lane  = threadIdx.x & 63;
    const int wslot = __builtin_amdgcn_readfirstlane((int)(threadIdx.x >> 6));
    const int b     = blockIdx.x * 4 + wslot;

    const int g  = lane & 31;
    const int g2 = (g < G2n) ? g : (G2n - 1);
    const int j1 = lane & 7;
    const int j2 = g % H2n;

    float wih1[Fn];
#pragma unroll
    for (int k = 0; k < Fn; ++k) wih1[k] = W_ih1[g * Fn + k];
    float whh1[H1n];
#pragma unroll
    for (int k = 0; k < H1n; ++k) whh1[k] = W_hh1[g * H1n + k];
    const float bias1 = b_ih1[g] + b_hh1[g];

    float wih2[H1n];
#pragma unroll
    for (int k = 0; k < H1n; ++k) wih2[k] = W_ih2[g2 * H1n + k];
    float whh2[H2n];
#pragma unroll
    for (int k = 0; k < H2n; ++k) whh2[k] = W_hh2[g2 * H2n + k];
    const float bias2 = b_ih2[g2] + b_hh2[g2];

    const bool t1 = (g >= 16 && g < 24);
    const float A1 = t1 ? 2.f : 1.f, Bc1 = t1 ? -2.f : -1.f, C1 = t1 ? -1.f : 0.f;
    const bool t2 = (g2 >= 12 && g2 < 18);
    const float A2 = t2 ? 2.f : 1.f, Bc2 = t2 ? -2.f : -1.f, C2 = t2 ? -1.f : 0.f;

    float h1all[H1n], th1all[H1n], h2all[H2n];
#pragma unroll
    for (int k = 0; k < H1n; ++k) { h1all[k] = 0.f; th1all[k] = 0.f; }
#pragma unroll
    for (int k = 0; k < H2n; ++k) h2all[k] = 0.f;
    float c1 = 0.f, c2 = 0.f;

    const float* __restrict__ xb = x + (size_t)b * Tn * Fn;

    float xgv;
    {
        float a = bias1;
#pragma unroll
        for (int k = 0; k < Fn; ++k) a = fmaf(xb[k], wih1[k], a);
        xgv = a;
    }

    for (int t = 0; t < Tn; ++t) {
        const float* __restrict__ xn = xb + (size_t)((t + 1 < Tn) ? (t + 1) : t) * Fn;
        float xs[Fn];
#pragma unroll
        for (int k = 0; k < Fn; ++k) xs[k] = xn[k];

        float a = xgv;
#pragma unroll
        for (int k = 0; k < H1n; ++k) a = fmaf(h1all[k], whh1[k], a);
        const float gv = act_abc(A1, Bc1, C1, a);

        const float iv  = __shfl(gv, j1);
        const float fv  = __shfl(gv, j1 + 8);
        const float gcv = __shfl(gv, j1 + 16);
        const float ov  = __shfl(gv, j1 + 24);
        c1 = fmaf(fv, c1, iv * gcv);
        const float h1v  = ov * ftanh(c1);
        const float th1v = ftanh(h1v);

        if (lane < H1n) { sm[wslot][lane] = h1v; sm[wslot][8 + lane] = th1v; }
        __builtin_amdgcn_wave_barrier();
        {
            const float4 v0 = *(const float4*)&sm[wslot][0];
            const float4 v1 = *(const float4*)&sm[wslot][4];
            const float4 v2 = *(const float4*)&sm[wslot][8];
            const float4 v3 = *(const float4*)&sm[wslot][12];
            h1all[0] = v0.x; h1all[1] = v0.y; h1all[2] = v0.z; h1all[3] = v0.w;
            h1all[4] = v1.x; h1all[5] = v1.y; h1all[6] = v1.z; h1all[7] = v1.w;
            th1all[0] = v2.x; th1all[1] = v2.y; th1all[2] = v2.z; th1all[3] = v2.w;
            th1all[4] = v3.x; th1all[5] = v3.y; th1all[6] = v3.z; th1all[7] = v3.w;
        }

        float a2 = bias2;
#pragma unroll
        for (int k = 0; k < H1n; ++k) a2 = fmaf(th1all[k], wih2[k], a2);
#pragma unroll
        for (int k = 0; k < H2n; ++k) a2 = fmaf(h2all[k], whh2[k], a2);
        const float gv2 = act_abc(A2, Bc2, C2, a2);

        const float iv2  = __shfl(gv2, j2);
        const float fv2  = __shfl(gv2, j2 + 6);
        const float gcv2 = __shfl(gv2, j2 + 12);
        const float ov2  = __shfl(gv2, j2 + 18);
        c2 = fmaf(fv2, c2, iv2 * gcv2);
        const float h2v = ov2 * ftanh(c2);

        if (lane < H2n) sm[wslot][16 + lane] = h2v;
        __builtin_amdgcn_wave_barrier();
        {
            const float4 v4 = *(const float4*)&sm[wslot][16];
            const float2 v5 = *(const float2*)&sm[wslot][20];
            h2all[0] = v4.x; h2all[1] = v4.y; h2all[2] = v4.z; h2all[3] = v4.w;
            h2all[4] = v5.x; h2all[5] = v5.y;
        }

        float an = bias1;
#pragma unroll
        for (int k = 0; k < Fn; ++k) an = fmaf(xs[k], wih1[k], an);
        xgv = an;
    }

    if (lane == 0) {
        float a = b_fc[0];
#pragma unroll
        for (int k = 0; k < H2n; ++k) a = fmaf(ftanh(h2all[k]), W_fc[k], a);
        out[b] = frcp(1.0f + __expf(-a));
    }
}

extern "C" void kernel_launch(void* const* d_in, const int* in_sizes, int n_in,
                              void* d_out, int out_size, void* d_ws, size_t ws_size,
                              hipStream_t stream) {
    (void)in_sizes; (void)n_in; (void)out_size;
    const float* x     = (const float*)d_in[0];
    const float* W_ih1 = (const float*)d_in[1];
    const float* W_hh1 = (const float*)d_in[2];
    const float* b_ih1 = (const float*)d_in[3];
    const float* b_hh1 = (const float*)d_in[4];
    const float* W_ih2 = (const float*)d_in[5];
    const float* W_hh2 = (const float*)d_in[6];
    const float* b_ih2 = (const float*)d_in[7];
    const float* b_hh2 = (const float*)d_in[8];
    const float* W_fc  = (const float*)d_in[9];
    const float* b_fc  = (const float*)d_in[10];
    float* out = (float*)d_out;

    const size_t need = (size_t)Bn * Tn * G1n * sizeof(float);   // 262 MB
    if (ws_size >= need) {
        float* xg = (float*)d_ws;
        xg_pass<<<dim3(Bn), dim3(256), 0, stream>>>(x, W_ih1, b_ih1, b_hh1, xg);
        lstm_rec<<<dim3(Bn / 4), dim3(256), 0, stream>>>(xg, W_hh1, W_ih2, W_hh2,
                                                         b_ih2, b_hh2, W_fc, b_fc, out);
    } else {
        lstm_fused<<<dim3(Bn / 4), dim3(256), 0, stream>>>(x, W_ih1, W_hh1, b_ih1, b_hh1,
                                                           W_ih2, W_hh2, b_ih2, b_hh2,
                                                           W_fc, b_fc, out);
    }
}